// Round 19
// baseline (566.052 us; speedup 1.0000x reference)
//
#include <hip/hip_runtime.h>

#define E_NUM 8
#define FFN_DIM 8192
#define D_DIM 2048
#define T_DIM 4096

using bf16x8 = __attribute__((ext_vector_type(8))) short;
using f32x4  = __attribute__((ext_vector_type(4))) float;
using u16x8  = __attribute__((ext_vector_type(8))) unsigned short;

__device__ __forceinline__ unsigned short f2bf(float f) {
  union { float f; unsigned int u; } v; v.f = f;
  unsigned int u = v.u;
  unsigned int r = (u + 0x7FFFu + ((u >> 16) & 1u)) >> 16;
  return (unsigned short)r;
}

__device__ __forceinline__ void gload16(const unsigned short* g, const unsigned short* l) {
  __builtin_amdgcn_global_load_lds(
      (const __attribute__((address_space(1))) void*)g,
      (__attribute__((address_space(3))) void*)l, 16, 0, 0);
}

// ---------- prep: merged convert(w1|v1|x) + transpose(w2), blockIdx.y 0-3 ----------
__global__ __launch_bounds__(512) void prep4_kernel(
    const float* __restrict__ x,  const float* __restrict__ w1,
    const float* __restrict__ v1, const float* __restrict__ w2,
    const int* __restrict__ eidx,
    unsigned short* __restrict__ Xb,  unsigned short* __restrict__ W1b,
    unsigned short* __restrict__ V1b, unsigned short* __restrict__ W2T) {
  __shared__ unsigned short tile[64][72];
  const long slab = (long)FFN_DIM * D_DIM;
  const int tid = threadIdx.x;

  if (blockIdx.y == 3) {
    const float* src = w2 + (long)(*eidx) * slab;
    int d0 = (blockIdx.x & 31) << 6;    // D/64 = 32
    int f0 = (blockIdx.x >> 5) << 6;    // FFN/64 = 128
#pragma unroll
    for (int p = 0; p < 2; ++p) {
      int f = p * 32 + (tid >> 4);
      int dc = (tid & 15) * 4;
      float4 v = *(const float4*)(src + (long)(f0 + f) * D_DIM + d0 + dc);
      tile[f][dc + 0] = f2bf(v.x); tile[f][dc + 1] = f2bf(v.y);
      tile[f][dc + 2] = f2bf(v.z); tile[f][dc + 3] = f2bf(v.w);
    }
    __syncthreads();
    int d = tid >> 3;
    int fc = (tid & 7) * 8;
    u16x8 o;
#pragma unroll
    for (int j = 0; j < 8; ++j) o[j] = tile[fc + j][d];
    *(u16x8*)(W2T + (long)(d0 + d) * FFN_DIM + f0 + fc) = o;
    return;
  }

  const float* src;
  unsigned short* dst;
  long n;
  if (blockIdx.y == 0)      { src = w1 + (long)(*eidx) * slab; dst = W1b; n = slab; }
  else if (blockIdx.y == 1) { src = v1 + (long)(*eidx) * slab; dst = V1b; n = slab; }
  else                      { src = x;                          dst = Xb;  n = (long)T_DIM * D_DIM; }
  long stride = (long)gridDim.x * blockDim.x;
  for (long i = (long)blockIdx.x * blockDim.x + tid; i * 8 < n; i += stride) {
    long e = i * 8;
    const float4* p = (const float4*)(src + e);
    float4 f0 = p[0], f1 = p[1];
    u16x8 o;
    o[0] = f2bf(f0.x); o[1] = f2bf(f0.y); o[2] = f2bf(f0.z); o[3] = f2bf(f0.w);
    o[4] = f2bf(f1.x); o[5] = f2bf(f1.y); o[6] = f2bf(f1.z); o[7] = f2bf(f1.w);
    *(u16x8*)(dst + e) = o;
  }
}

// Counted vmcnt waits with memory clobber (stage issues pinned to their side
// of the wait so the outstanding-count arithmetic stays exact — r8/r9 lesson).
#define VMCNT8 asm volatile("s_waitcnt vmcnt(8)" ::: "memory")
#define VMCNT0 asm volatile("s_waitcnt vmcnt(0)" ::: "memory")
// Barrier = lgkmcnt(0) drain + s_barrier (opaque). Invariant: a ds_read and a
// later global_load_lds stage overwriting the same LDS rows must be separated
// by one of these (r7-r10 lesson). vmcnt NOT drained here.
#define BAR asm volatile("s_waitcnt lgkmcnt(0)\n\ts_barrier" ::: "memory")
#define PRIO1 __builtin_amdgcn_s_setprio(1)
#define PRIO0 __builtin_amdgcn_s_setprio(0)

// ---------- GEMM1 fused: 128x64(dual) tile, BK=64, 4 waves, 2 blocks/CU ----------
// LDS 64KB: sA 2x(128x64), sB1 2x(64x64), sB2 2x(64x64) bf16.
// 4096 blocks = 2/CU (TLP overlap, r18-proven on gemm2). 4 waves 2Mx2N,
// wave 64x32 per GEMM. Schedule (r5/r18-proven): {16 reads; 32 MFMA}
// drain-BAR {stage t+2->cur (8 rounds); vmcnt(8)} BAR.
// Ledger: prologue t0+t1 = 16 out, vmcnt(8) leaves t1; per iter 16 out ->
// vmcnt(8) drains t+1 exactly; tails vmcnt(0). Rows 128B -> full bursts.
// XCD n-banding: each XCD owns a 16-n-tile band (8MB B-slice ~L2-resident,
// reused by its 32 m-tiles).
__global__ __launch_bounds__(256, 2) void gemm1_silu(
    const unsigned short* __restrict__ Xb,    // (4096,2048)
    const unsigned short* __restrict__ W1b,   // (8192,2048)
    const unsigned short* __restrict__ V1b,   // (8192,2048)
    unsigned short* __restrict__ Hb) {        // (4096,8192)
  __shared__ __align__(16) unsigned short sA[2 * 8192];    // [buf][128x64]
  __shared__ __align__(16) unsigned short sB1[2 * 4096];   // [buf][64x64]
  __shared__ __align__(16) unsigned short sB2[2 * 4096];

  const int tid = threadIdx.x;
  const int wv = tid >> 6, l = tid & 63;
  const int wm = wv >> 1, wn = wv & 1;        // 2M x 2N
  const int kq = l >> 4, lr = l & 15;
  const int bsw = (blockIdx.x & 7) * 512 + (blockIdx.x >> 3);  // 4096 = 8*512
  const int m0 = (bsw & 31) << 7;             // 32 m-tiles (m-fastest in XCD)
  const int n0 = (bsw >> 5) << 6;             // 128 n-tiles (16 per XCD band)

  const int rsub = tid >> 3;                  // 0..31 (row within 32-row round)
  const int sslot8 = ((tid & 7) ^ (rsub & 7)) << 3;
  const unsigned short* gA  = Xb  + (long)(m0 + rsub) * D_DIM + sslot8;
  const unsigned short* gB1 = W1b + (long)(n0 + rsub) * D_DIM + sslot8;
  const unsigned short* gB2 = V1b + (long)(n0 + rsub) * D_DIM + sslot8;

  // one 32-row round per call (256 thr x 16B = 2048 elems)
#define STG1(gbase, r_, tc_, lbase) \
  gload16((gbase) + (long)((r_) * 32) * D_DIM + (tc_), (lbase) + (r_) * 2048 + wv * 512)

  int aoff[4], boff[2];
#pragma unroll
  for (int j = 0; j < 4; ++j) {
    int row = wm * 64 + j * 16 + lr;
    aoff[j] = row * 64 + ((kq ^ (row & 7)) << 3);
  }
#pragma unroll
  for (int g = 0; g < 2; ++g) {
    int row = wn * 32 + g * 16 + lr;
    boff[g] = row * 64 + ((kq ^ (row & 7)) << 3);
  }

  f32x4 acc1[4][2], acc2[4][2];
  f32x4 z = {0.f, 0.f, 0.f, 0.f};
#pragma unroll
  for (int j = 0; j < 4; ++j)
#pragma unroll
    for (int g = 0; g < 2; ++g) { acc1[j][g] = z; acc2[j][g] = z; }

  // prologue: stage t0 -> buf0 (A r0-3, B1 r0-1, B2 r0-1), t1 -> buf1; vmcnt(8)
  STG1(gA, 0, 0, sA); STG1(gA, 1, 0, sA); STG1(gA, 2, 0, sA); STG1(gA, 3, 0, sA);
  STG1(gB1, 0, 0, sB1); STG1(gB1, 1, 0, sB1);
  STG1(gB2, 0, 0, sB2); STG1(gB2, 1, 0, sB2);
  STG1(gA, 0, 64, sA + 8192); STG1(gA, 1, 64, sA + 8192);
  STG1(gA, 2, 64, sA + 8192); STG1(gA, 3, 64, sA + 8192);
  STG1(gB1, 0, 64, sB1 + 4096); STG1(gB1, 1, 64, sB1 + 4096);
  STG1(gB2, 0, 64, sB2 + 4096); STG1(gB2, 1, 64, sB2 + 4096);
  VMCNT8;
  BAR;

  const int NT = D_DIM / 64;  // 32
  for (int t = 0; t < NT; ++t) {
    const int cur = t & 1;
    const unsigned short* Ac  = sA  + cur * 8192;
    const unsigned short* B1c = sB1 + cur * 4096;
    const unsigned short* B2c = sB2 + cur * 4096;
    unsigned short* AcW  = (unsigned short*)sA  + cur * 8192;
    unsigned short* B1cW = (unsigned short*)sB1 + cur * 4096;
    unsigned short* B2cW = (unsigned short*)sB2 + cur * 4096;
    bf16x8 aA[4][2], b1[2][2], b2[2][2];

    // reads (consumed in-iter; BAR's lgkm0 drain -> WAR-safe)
#pragma unroll
    for (int j = 0; j < 4; ++j) {
      aA[j][0] = *(const bf16x8*)(Ac + aoff[j]);
      aA[j][1] = *(const bf16x8*)(Ac + (aoff[j] ^ 32));
    }
#pragma unroll
    for (int g = 0; g < 2; ++g) {
      b1[g][0] = *(const bf16x8*)(B1c + boff[g]);
      b1[g][1] = *(const bf16x8*)(B1c + (boff[g] ^ 32));
      b2[g][0] = *(const bf16x8*)(B2c + boff[g]);
      b2[g][1] = *(const bf16x8*)(B2c + (boff[g] ^ 32));
    }
    PRIO1;
#pragma unroll
    for (int j = 0; j < 4; ++j)
#pragma unroll
      for (int g = 0; g < 2; ++g) {
        acc1[j][g] = __builtin_amdgcn_mfma_f32_16x16x32_bf16(aA[j][0], b1[g][0], acc1[j][g], 0, 0, 0);
        acc1[j][g] = __builtin_amdgcn_mfma_f32_16x16x32_bf16(aA[j][1], b1[g][1], acc1[j][g], 0, 0, 0);
        acc2[j][g] = __builtin_amdgcn_mfma_f32_16x16x32_bf16(aA[j][0], b2[g][0], acc2[j][g], 0, 0, 0);
        acc2[j][g] = __builtin_amdgcn_mfma_f32_16x16x32_bf16(aA[j][1], b2[g][1], acc2[j][g], 0, 0, 0);
      }
    PRIO0;
    BAR;   // all waves' reads of cur sampled (lgkm0 inside)

    if (t + 2 < NT) {
      const int tc2 = (t + 2) << 6;
      STG1(gA, 0, tc2, AcW); STG1(gA, 1, tc2, AcW);
      STG1(gA, 2, tc2, AcW); STG1(gA, 3, tc2, AcW);
      STG1(gB1, 0, tc2, B1cW); STG1(gB1, 1, tc2, B1cW);
      STG1(gB2, 0, tc2, B2cW); STG1(gB2, 1, tc2, B2cW);
      VMCNT8;                    // drains exactly tile t+1 (16 out -> 8)
    } else if (t + 1 < NT) {
      VMCNT0;
    }
    BAR;
  }

  // epilogue: h = silu(x1)*x2, bf16
#pragma unroll
  for (int j = 0; j < 4; ++j)
#pragma unroll
    for (int g = 0; g < 2; ++g)
#pragma unroll
      for (int r = 0; r < 4; ++r) {
        int row = m0 + wm * 64 + j * 16 + kq * 4 + r;
        int col = n0 + wn * 32 + g * 16 + lr;
        float x1 = acc1[j][g][r], x2 = acc2[j][g][r];
        float hv = x1 / (1.f + __expf(-x1)) * x2;
        Hb[(long)row * FFN_DIM + col] = f2bf(hv);
      }
#undef STG1
}

// ---------- GEMM2 (r18-proven, FROZEN): 128x128, BK=64, 4 waves, 2 blocks/CU ----
__global__ __launch_bounds__(256, 2) void gemm2(
    const unsigned short* __restrict__ Hb,    // (4096,8192)
    const unsigned short* __restrict__ W2T,   // (2048,8192)
    float* __restrict__ out) {                // (4096,2048)
  __shared__ __align__(16) unsigned short sA[2 * 8192];   // [buf][128x64]
  __shared__ __align__(16) unsigned short sB[2 * 8192];

  const int tid = threadIdx.x;
  const int wv = tid >> 6, l = tid & 63;
  const int wm = wv >> 1, wn = wv & 1;        // 2M x 2N, wave 64x64
  const int kq = l >> 4, lr = l & 15;
  const int bsw = (blockIdx.x & 7) * 64 + (blockIdx.x >> 3);   // 512 = 8*64
  const int m0 = (bsw >> 4) << 7;             // 32 m-tiles
  const int n0 = (bsw & 15) << 7;             // 16 n-tiles

  const int rsub = tid >> 3;                  // 0..31
  const int sslot8 = ((tid & 7) ^ (rsub & 7)) << 3;
  const unsigned short* gA = Hb  + (long)(m0 + rsub) * FFN_DIM + sslot8;
  const unsigned short* gB = W2T + (long)(n0 + rsub) * FFN_DIM + sslot8;

#define STG2(gbase, r_, tc_, lbase) \
  gload16((gbase) + (long)((r_) * 32) * FFN_DIM + (tc_), (lbase) + (r_) * 2048 + wv * 512)

  int aoff[4], boff[4];
#pragma unroll
  for (int f = 0; f < 4; ++f) {
    int row = wm * 64 + f * 16 + lr;
    aoff[f] = row * 64 + ((kq ^ (row & 7)) << 3);
  }
#pragma unroll
  for (int g = 0; g < 4; ++g) {
    int row = wn * 64 + g * 16 + lr;
    boff[g] = row * 64 + ((kq ^ (row & 7)) << 3);
  }

  f32x4 acc[4][4];
  f32x4 z = {0.f, 0.f, 0.f, 0.f};
#pragma unroll
  for (int f = 0; f < 4; ++f)
#pragma unroll
    for (int g = 0; g < 4; ++g) acc[f][g] = z;

  STG2(gA, 0, 0, sA); STG2(gA, 1, 0, sA); STG2(gA, 2, 0, sA); STG2(gA, 3, 0, sA);
  STG2(gB, 0, 0, sB); STG2(gB, 1, 0, sB); STG2(gB, 2, 0, sB); STG2(gB, 3, 0, sB);
  STG2(gA, 0, 64, sA + 8192); STG2(gA, 1, 64, sA + 8192);
  STG2(gA, 2, 64, sA + 8192); STG2(gA, 3, 64, sA + 8192);
  STG2(gB, 0, 64, sB + 8192); STG2(gB, 1, 64, sB + 8192);
  STG2(gB, 2, 64, sB + 8192); STG2(gB, 3, 64, sB + 8192);
  VMCNT8;
  BAR;

  const int NT = FFN_DIM / 64;  // 128
  for (int t = 0; t < NT; ++t) {
    const int cur = t & 1;
    const unsigned short* Ac = sA + cur * 8192;
    const unsigned short* Bc = sB + cur * 8192;
    unsigned short* AcW = (unsigned short*)sA + cur * 8192;
    unsigned short* BcW = (unsigned short*)sB + cur * 8192;
    bf16x8 af[4][2], bf_[4][2];

#pragma unroll
    for (int f = 0; f < 4; ++f) {
      af[f][0] = *(const bf16x8*)(Ac + aoff[f]);
      af[f][1] = *(const bf16x8*)(Ac + (aoff[f] ^ 32));
    }
#pragma unroll
    for (int g = 0; g < 4; ++g) {
      bf_[g][0] = *(const bf16x8*)(Bc + boff[g]);
      bf_[g][1] = *(const bf16x8*)(Bc + (boff[g] ^ 32));
    }
    PRIO1;
#pragma unroll
    for (int f = 0; f < 4; ++f)
#pragma unroll
      for (int g = 0; g < 4; ++g) {
        acc[f][g] = __builtin_amdgcn_mfma_f32_16x16x32_bf16(af[f][0], bf_[g][0], acc[f][g], 0, 0, 0);
        acc[f][g] = __builtin_amdgcn_mfma_f32_16x16x32_bf16(af[f][1], bf_[g][1], acc[f][g], 0, 0, 0);
      }
    PRIO0;
    BAR;

    if (t + 2 < NT) {
      const int tc2 = (t + 2) << 6;
      STG2(gA, 0, tc2, AcW); STG2(gA, 1, tc2, AcW);
      STG2(gA, 2, tc2, AcW); STG2(gA, 3, tc2, AcW);
      STG2(gB, 0, tc2, BcW); STG2(gB, 1, tc2, BcW);
      STG2(gB, 2, tc2, BcW); STG2(gB, 3, tc2, BcW);
      VMCNT8;
    } else if (t + 1 < NT) {
      VMCNT0;
    }
    BAR;
  }

#pragma unroll
  for (int f = 0; f < 4; ++f)
#pragma unroll
    for (int g = 0; g < 4; ++g)
#pragma unroll
      for (int r = 0; r < 4; ++r) {
        int row = m0 + wm * 64 + f * 16 + kq * 4 + r;
        int col = n0 + wn * 64 + g * 16 + lr;
        out[(long)row * D_DIM + col] = acc[f][g][r];
      }
#undef STG2
}

extern "C" void kernel_launch(void* const* d_in, const int* in_sizes, int n_in,
                              void* d_out, int out_size, void* d_ws, size_t ws_size,
                              hipStream_t stream) {
  const float* x  = (const float*)d_in[0];
  const float* w1 = (const float*)d_in[1];
  const float* v1 = (const float*)d_in[2];
  const float* w2 = (const float*)d_in[3];
  const int* eidx = (const int*)d_in[4];

  char* ws = (char*)d_ws;
  unsigned short* Xb  = (unsigned short*)(ws);                  // 16 MiB
  unsigned short* W1b = (unsigned short*)(ws + (16l << 20));    // 32 MiB
  unsigned short* V1b = (unsigned short*)(ws + (48l << 20));    // 32 MiB
  unsigned short* W2T = (unsigned short*)(ws + (80l << 20));    // 32 MiB
  unsigned short* Hb  = (unsigned short*)(ws + (112l << 20));   // 64 MiB
  float* out = (float*)d_out;

  prep4_kernel<<<dim3(4096, 4), 512, 0, stream>>>(x, w1, v1, w2, eidx, Xb, W1b, V1b, W2T);
  gemm1_silu<<<4096, 256, 0, stream>>>(Xb, W1b, V1b, Hb);
  gemm2<<<512, 256, 0, stream>>>(Hb, W2T, out);
}

// Round 20
// 468.832 us; speedup vs baseline: 1.2074x; 1.2074x over previous
//
#include <hip/hip_runtime.h>

#define E_NUM 8
#define FFN_DIM 8192
#define D_DIM 2048
#define T_DIM 4096

using bf16x8 = __attribute__((ext_vector_type(8))) short;
using f32x4  = __attribute__((ext_vector_type(4))) float;
using u16x8  = __attribute__((ext_vector_type(8))) unsigned short;

__device__ __forceinline__ unsigned short f2bf(float f) {
  union { float f; unsigned int u; } v; v.f = f;
  unsigned int u = v.u;
  unsigned int r = (u + 0x7FFFu + ((u >> 16) & 1u)) >> 16;
  return (unsigned short)r;
}

__device__ __forceinline__ void gload16(const unsigned short* g, const unsigned short* l) {
  __builtin_amdgcn_global_load_lds(
      (const __attribute__((address_space(1))) void*)g,
      (__attribute__((address_space(3))) void*)l, 16, 0, 0);
}

// ---------- prep: merged convert(w1|v1|x) + transpose(w2), blockIdx.y 0-3 ----------
__global__ __launch_bounds__(512) void prep4_kernel(
    const float* __restrict__ x,  const float* __restrict__ w1,
    const float* __restrict__ v1, const float* __restrict__ w2,
    const int* __restrict__ eidx,
    unsigned short* __restrict__ Xb,  unsigned short* __restrict__ W1b,
    unsigned short* __restrict__ V1b, unsigned short* __restrict__ W2T) {
  __shared__ unsigned short tile[64][72];
  const long slab = (long)FFN_DIM * D_DIM;
  const int tid = threadIdx.x;

  if (blockIdx.y == 3) {
    const float* src = w2 + (long)(*eidx) * slab;
    int d0 = (blockIdx.x & 31) << 6;    // D/64 = 32
    int f0 = (blockIdx.x >> 5) << 6;    // FFN/64 = 128
#pragma unroll
    for (int p = 0; p < 2; ++p) {
      int f = p * 32 + (tid >> 4);
      int dc = (tid & 15) * 4;
      float4 v = *(const float4*)(src + (long)(f0 + f) * D_DIM + d0 + dc);
      tile[f][dc + 0] = f2bf(v.x); tile[f][dc + 1] = f2bf(v.y);
      tile[f][dc + 2] = f2bf(v.z); tile[f][dc + 3] = f2bf(v.w);
    }
    __syncthreads();
    int d = tid >> 3;
    int fc = (tid & 7) * 8;
    u16x8 o;
#pragma unroll
    for (int j = 0; j < 8; ++j) o[j] = tile[fc + j][d];
    *(u16x8*)(W2T + (long)(d0 + d) * FFN_DIM + f0 + fc) = o;
    return;
  }

  const float* src;
  unsigned short* dst;
  long n;
  if (blockIdx.y == 0)      { src = w1 + (long)(*eidx) * slab; dst = W1b; n = slab; }
  else if (blockIdx.y == 1) { src = v1 + (long)(*eidx) * slab; dst = V1b; n = slab; }
  else                      { src = x;                          dst = Xb;  n = (long)T_DIM * D_DIM; }
  long stride = (long)gridDim.x * blockDim.x;
  for (long i = (long)blockIdx.x * blockDim.x + tid; i * 8 < n; i += stride) {
    long e = i * 8;
    const float4* p = (const float4*)(src + e);
    float4 f0 = p[0], f1 = p[1];
    u16x8 o;
    o[0] = f2bf(f0.x); o[1] = f2bf(f0.y); o[2] = f2bf(f0.z); o[3] = f2bf(f0.w);
    o[4] = f2bf(f1.x); o[5] = f2bf(f1.y); o[6] = f2bf(f1.z); o[7] = f2bf(f1.w);
    *(u16x8*)(dst + e) = o;
  }
}

// Counted vmcnt waits with memory clobber (r8/r9 lesson: pin stage issues).
#define VMCNT8 asm volatile("s_waitcnt vmcnt(8)" ::: "memory")
#define VMCNT0 asm volatile("s_waitcnt vmcnt(0)" ::: "memory")
// Barrier = lgkmcnt(0) drain + s_barrier (opaque). r7-r10 lesson: ds_read and
// later same-rows stage must be separated by one of these.
#define BAR asm volatile("s_waitcnt lgkmcnt(0)\n\ts_barrier" ::: "memory")
#define PRIO1 __builtin_amdgcn_s_setprio(1)
#define PRIO0 __builtin_amdgcn_s_setprio(0)

// ---------- GEMM1 fused: 128x128 dual-B, SINGLE-buffered, 2 blocks/CU ----------
// LDS 48KB: sA 128x64, sB1 128x64, sB2 128x64 (no double-buffer).
// 2048 blocks, 4 waves (2Mx2N), wave 64x64 per GEMM -> 64 MFMA : 24 reads
// per wave-tile (2.67 density; dual-GEMM shares A-frags).
// TLP hides the per-tile vmcnt(0): the co-resident block's MFMA phase covers
// this block's load drain (m114 / r18-proven mechanism).
// Schedule (simplest race-free form): {reads; MFMA} drain-BAR
// {stage t+1; vmcnt(0)} BAR. No read-ahead; reads consumed in-iter.
// XCD chunking m-fastest: each XCD's A-band = 512 rows = 2MB (L2-resident);
// B streams via L3.
__global__ __launch_bounds__(256, 2) void gemm1_silu(
    const unsigned short* __restrict__ Xb,    // (4096,2048)
    const unsigned short* __restrict__ W1b,   // (8192,2048)
    const unsigned short* __restrict__ V1b,   // (8192,2048)
    unsigned short* __restrict__ Hb) {        // (4096,8192)
  __shared__ __align__(16) unsigned short sA[8192];    // 128x64
  __shared__ __align__(16) unsigned short sB1[8192];   // 128x64
  __shared__ __align__(16) unsigned short sB2[8192];

  const int tid = threadIdx.x;
  const int wv = tid >> 6, l = tid & 63;
  const int wm = wv >> 1, wn = wv & 1;        // 2M x 2N, wave 64x64 per GEMM
  const int kq = l >> 4, lr = l & 15;
  const int bsw = (blockIdx.x & 7) * 256 + (blockIdx.x >> 3);  // 2048 = 8*256
  const int m0 = (bsw & 31) << 7;             // 32 m-tiles (m-fastest in XCD)
  const int n0 = (bsw >> 5) << 7;             // 64 n-tiles (8 per XCD band)

  const int rsub = tid >> 3;                  // 0..31 (row within 32-row round)
  const int sslot8 = ((tid & 7) ^ (rsub & 7)) << 3;
  const unsigned short* gA  = Xb  + (long)(m0 + rsub) * D_DIM + sslot8;
  const unsigned short* gB1 = W1b + (long)(n0 + rsub) * D_DIM + sslot8;
  const unsigned short* gB2 = V1b + (long)(n0 + rsub) * D_DIM + sslot8;

  // one 32-row round (256 thr x 16B = 2048 shorts); 4 rounds per operand
#define STG1(gbase, r_, tc_, lbase) \
  gload16((gbase) + (long)((r_) * 32) * D_DIM + (tc_), (lbase) + (r_) * 2048 + wv * 512)
#define STAGE_TILE(tc_) do { \
    STG1(gA, 0, tc_, sA); STG1(gA, 1, tc_, sA); STG1(gA, 2, tc_, sA); STG1(gA, 3, tc_, sA); \
    STG1(gB1, 0, tc_, sB1); STG1(gB1, 1, tc_, sB1); STG1(gB1, 2, tc_, sB1); STG1(gB1, 3, tc_, sB1); \
    STG1(gB2, 0, tc_, sB2); STG1(gB2, 1, tc_, sB2); STG1(gB2, 2, tc_, sB2); STG1(gB2, 3, tc_, sB2); \
  } while (0)

  int aoff[4], boff[4];
#pragma unroll
  for (int f = 0; f < 4; ++f) {
    int row = wm * 64 + f * 16 + lr;
    aoff[f] = row * 64 + ((kq ^ (row & 7)) << 3);
  }
#pragma unroll
  for (int g = 0; g < 4; ++g) {
    int row = wn * 64 + g * 16 + lr;
    boff[g] = row * 64 + ((kq ^ (row & 7)) << 3);
  }

  f32x4 acc1[4][4], acc2[4][4];
  f32x4 z = {0.f, 0.f, 0.f, 0.f};
#pragma unroll
  for (int f = 0; f < 4; ++f)
#pragma unroll
    for (int g = 0; g < 4; ++g) { acc1[f][g] = z; acc2[f][g] = z; }

  // prologue: stage tile 0; full drain; barrier
  STAGE_TILE(0);
  VMCNT0;
  BAR;

  const int NT = D_DIM / 64;  // 32
  for (int t = 0; t < NT; ++t) {
    bf16x8 aA[4][2], b[4][2];

    // reads A (shared by both GEMMs)
#pragma unroll
    for (int f = 0; f < 4; ++f) {
      aA[f][0] = *(const bf16x8*)(sA + aoff[f]);
      aA[f][1] = *(const bf16x8*)(sA + (aoff[f] ^ 32));
    }
    // B1 reads + MFMA acc1
#pragma unroll
    for (int g = 0; g < 4; ++g) {
      b[g][0] = *(const bf16x8*)(sB1 + boff[g]);
      b[g][1] = *(const bf16x8*)(sB1 + (boff[g] ^ 32));
    }
    PRIO1;
#pragma unroll
    for (int f = 0; f < 4; ++f)
#pragma unroll
      for (int g = 0; g < 4; ++g) {
        acc1[f][g] = __builtin_amdgcn_mfma_f32_16x16x32_bf16(aA[f][0], b[g][0], acc1[f][g], 0, 0, 0);
        acc1[f][g] = __builtin_amdgcn_mfma_f32_16x16x32_bf16(aA[f][1], b[g][1], acc1[f][g], 0, 0, 0);
      }
    PRIO0;
    // B2 reads + MFMA acc2 (b registers reused -> caps live VGPRs)
#pragma unroll
    for (int g = 0; g < 4; ++g) {
      b[g][0] = *(const bf16x8*)(sB2 + boff[g]);
      b[g][1] = *(const bf16x8*)(sB2 + (boff[g] ^ 32));
    }
    PRIO1;
#pragma unroll
    for (int f = 0; f < 4; ++f)
#pragma unroll
      for (int g = 0; g < 4; ++g) {
        acc2[f][g] = __builtin_amdgcn_mfma_f32_16x16x32_bf16(aA[f][0], b[g][0], acc2[f][g], 0, 0, 0);
        acc2[f][g] = __builtin_amdgcn_mfma_f32_16x16x32_bf16(aA[f][1], b[g][1], acc2[f][g], 0, 0, 0);
      }
    PRIO0;
    BAR;   // lgkm0 drain: all waves' reads of this tile sampled

    if (t + 1 < NT) {
      STAGE_TILE((t + 1) << 6);
      VMCNT0;                    // single-buffer: drain before reading
    }
    BAR;
  }

  // epilogue: h = silu(x1)*x2, bf16 (both GEMMs local to the wave)
#pragma unroll
  for (int f = 0; f < 4; ++f)
#pragma unroll
    for (int g = 0; g < 4; ++g)
#pragma unroll
      for (int r = 0; r < 4; ++r) {
        int row = m0 + wm * 64 + f * 16 + kq * 4 + r;
        int col = n0 + wn * 64 + g * 16 + lr;
        float x1 = acc1[f][g][r], x2 = acc2[f][g][r];
        float hv = x1 / (1.f + __expf(-x1)) * x2;
        Hb[(long)row * FFN_DIM + col] = f2bf(hv);
      }
#undef STG1
#undef STAGE_TILE
}

// ---------- GEMM2 (r18-proven, FROZEN): 128x128, BK=64, 4 waves, 2 blocks/CU ----
__global__ __launch_bounds__(256, 2) void gemm2(
    const unsigned short* __restrict__ Hb,    // (4096,8192)
    const unsigned short* __restrict__ W2T,   // (2048,8192)
    float* __restrict__ out) {                // (4096,2048)
  __shared__ __align__(16) unsigned short sA[2 * 8192];   // [buf][128x64]
  __shared__ __align__(16) unsigned short sB[2 * 8192];

  const int tid = threadIdx.x;
  const int wv = tid >> 6, l = tid & 63;
  const int wm = wv >> 1, wn = wv & 1;        // 2M x 2N, wave 64x64
  const int kq = l >> 4, lr = l & 15;
  const int bsw = (blockIdx.x & 7) * 64 + (blockIdx.x >> 3);   // 512 = 8*64
  const int m0 = (bsw >> 4) << 7;             // 32 m-tiles
  const int n0 = (bsw & 15) << 7;             // 16 n-tiles

  const int rsub = tid >> 3;                  // 0..31
  const int sslot8 = ((tid & 7) ^ (rsub & 7)) << 3;
  const unsigned short* gA = Hb  + (long)(m0 + rsub) * FFN_DIM + sslot8;
  const unsigned short* gB = W2T + (long)(n0 + rsub) * FFN_DIM + sslot8;

#define STG2(gbase, r_, tc_, lbase) \
  gload16((gbase) + (long)((r_) * 32) * FFN_DIM + (tc_), (lbase) + (r_) * 2048 + wv * 512)

  int aoff[4], boff[4];
#pragma unroll
  for (int f = 0; f < 4; ++f) {
    int row = wm * 64 + f * 16 + lr;
    aoff[f] = row * 64 + ((kq ^ (row & 7)) << 3);
  }
#pragma unroll
  for (int g = 0; g < 4; ++g) {
    int row = wn * 64 + g * 16 + lr;
    boff[g] = row * 64 + ((kq ^ (row & 7)) << 3);
  }

  f32x4 acc[4][4];
  f32x4 z = {0.f, 0.f, 0.f, 0.f};
#pragma unroll
  for (int f = 0; f < 4; ++f)
#pragma unroll
    for (int g = 0; g < 4; ++g) acc[f][g] = z;

  STG2(gA, 0, 0, sA); STG2(gA, 1, 0, sA); STG2(gA, 2, 0, sA); STG2(gA, 3, 0, sA);
  STG2(gB, 0, 0, sB); STG2(gB, 1, 0, sB); STG2(gB, 2, 0, sB); STG2(gB, 3, 0, sB);
  STG2(gA, 0, 64, sA + 8192); STG2(gA, 1, 64, sA + 8192);
  STG2(gA, 2, 64, sA + 8192); STG2(gA, 3, 64, sA + 8192);
  STG2(gB, 0, 64, sB + 8192); STG2(gB, 1, 64, sB + 8192);
  STG2(gB, 2, 64, sB + 8192); STG2(gB, 3, 64, sB + 8192);
  VMCNT8;
  BAR;

  const int NT = FFN_DIM / 64;  // 128
  for (int t = 0; t < NT; ++t) {
    const int cur = t & 1;
    const unsigned short* Ac = sA + cur * 8192;
    const unsigned short* Bc = sB + cur * 8192;
    unsigned short* AcW = (unsigned short*)sA + cur * 8192;
    unsigned short* BcW = (unsigned short*)sB + cur * 8192;
    bf16x8 af[4][2], bf_[4][2];

#pragma unroll
    for (int f = 0; f < 4; ++f) {
      af[f][0] = *(const bf16x8*)(Ac + aoff[f]);
      af[f][1] = *(const bf16x8*)(Ac + (aoff[f] ^ 32));
    }
#pragma unroll
    for (int g = 0; g < 4; ++g) {
      bf_[g][0] = *(const bf16x8*)(Bc + boff[g]);
      bf_[g][1] = *(const bf16x8*)(Bc + (boff[g] ^ 32));
    }
    PRIO1;
#pragma unroll
    for (int f = 0; f < 4; ++f)
#pragma unroll
      for (int g = 0; g < 4; ++g) {
        acc[f][g] = __builtin_amdgcn_mfma_f32_16x16x32_bf16(af[f][0], bf_[g][0], acc[f][g], 0, 0, 0);
        acc[f][g] = __builtin_amdgcn_mfma_f32_16x16x32_bf16(af[f][1], bf_[g][1], acc[f][g], 0, 0, 0);
      }
    PRIO0;
    BAR;

    if (t + 2 < NT) {
      const int tc2 = (t + 2) << 6;
      STG2(gA, 0, tc2, AcW); STG2(gA, 1, tc2, AcW);
      STG2(gA, 2, tc2, AcW); STG2(gA, 3, tc2, AcW);
      STG2(gB, 0, tc2, BcW); STG2(gB, 1, tc2, BcW);
      STG2(gB, 2, tc2, BcW); STG2(gB, 3, tc2, BcW);
      VMCNT8;
    } else if (t + 1 < NT) {
      VMCNT0;
    }
    BAR;
  }

#pragma unroll
  for (int f = 0; f < 4; ++f)
#pragma unroll
    for (int g = 0; g < 4; ++g)
#pragma unroll
      for (int r = 0; r < 4; ++r) {
        int row = m0 + wm * 64 + f * 16 + kq * 4 + r;
        int col = n0 + wn * 64 + g * 16 + lr;
        out[(long)row * D_DIM + col] = acc[f][g][r];
      }
#undef STG2
}

extern "C" void kernel_launch(void* const* d_in, const int* in_sizes, int n_in,
                              void* d_out, int out_size, void* d_ws, size_t ws_size,
                              hipStream_t stream) {
  const float* x  = (const float*)d_in[0];
  const float* w1 = (const float*)d_in[1];
  const float* v1 = (const float*)d_in[2];
  const float* w2 = (const float*)d_in[3];
  const int* eidx = (const int*)d_in[4];

  char* ws = (char*)d_ws;
  unsigned short* Xb  = (unsigned short*)(ws);                  // 16 MiB
  unsigned short* W1b = (unsigned short*)(ws + (16l << 20));    // 32 MiB
  unsigned short* V1b = (unsigned short*)(ws + (48l << 20));    // 32 MiB
  unsigned short* W2T = (unsigned short*)(ws + (80l << 20));    // 32 MiB
  unsigned short* Hb  = (unsigned short*)(ws + (112l << 20));   // 64 MiB
  float* out = (float*)d_out;

  prep4_kernel<<<dim3(4096, 4), 512, 0, stream>>>(x, w1, v1, w2, eidx, Xb, W1b, V1b, W2T);
  gemm1_silu<<<2048, 256, 0, stream>>>(Xb, W1b, V1b, Hb);
  gemm2<<<512, 256, 0, stream>>>(Hb, W2T, out);
}

// Round 21
// 439.626 us; speedup vs baseline: 1.2876x; 1.0664x over previous
//
#include <hip/hip_runtime.h>

#define E_NUM 8
#define FFN_DIM 8192
#define D_DIM 2048
#define T_DIM 4096

using bf16x8 = __attribute__((ext_vector_type(8))) short;
using f32x4  = __attribute__((ext_vector_type(4))) float;
using u16x8  = __attribute__((ext_vector_type(8))) unsigned short;

__device__ __forceinline__ unsigned short f2bf(float f) {
  union { float f; unsigned int u; } v; v.f = f;
  unsigned int u = v.u;
  unsigned int r = (u + 0x7FFFu + ((u >> 16) & 1u)) >> 16;
  return (unsigned short)r;
}

__device__ __forceinline__ void gload16(const unsigned short* g, const unsigned short* l) {
  __builtin_amdgcn_global_load_lds(
      (const __attribute__((address_space(1))) void*)g,
      (__attribute__((address_space(3))) void*)l, 16, 0, 0);
}

// ---------- prep: merged convert(w1|v1|x) + transpose(w2), blockIdx.y 0-3 ----------
__global__ __launch_bounds__(512) void prep4_kernel(
    const float* __restrict__ x,  const float* __restrict__ w1,
    const float* __restrict__ v1, const float* __restrict__ w2,
    const int* __restrict__ eidx,
    unsigned short* __restrict__ Xb,  unsigned short* __restrict__ W1b,
    unsigned short* __restrict__ V1b, unsigned short* __restrict__ W2T) {
  __shared__ unsigned short tile[64][72];
  const long slab = (long)FFN_DIM * D_DIM;
  const int tid = threadIdx.x;

  if (blockIdx.y == 3) {
    const float* src = w2 + (long)(*eidx) * slab;
    int d0 = (blockIdx.x & 31) << 6;    // D/64 = 32
    int f0 = (blockIdx.x >> 5) << 6;    // FFN/64 = 128
#pragma unroll
    for (int p = 0; p < 2; ++p) {
      int f = p * 32 + (tid >> 4);
      int dc = (tid & 15) * 4;
      float4 v = *(const float4*)(src + (long)(f0 + f) * D_DIM + d0 + dc);
      tile[f][dc + 0] = f2bf(v.x); tile[f][dc + 1] = f2bf(v.y);
      tile[f][dc + 2] = f2bf(v.z); tile[f][dc + 3] = f2bf(v.w);
    }
    __syncthreads();
    int d = tid >> 3;
    int fc = (tid & 7) * 8;
    u16x8 o;
#pragma unroll
    for (int j = 0; j < 8; ++j) o[j] = tile[fc + j][d];
    *(u16x8*)(W2T + (long)(d0 + d) * FFN_DIM + f0 + fc) = o;
    return;
  }

  const float* src;
  unsigned short* dst;
  long n;
  if (blockIdx.y == 0)      { src = w1 + (long)(*eidx) * slab; dst = W1b; n = slab; }
  else if (blockIdx.y == 1) { src = v1 + (long)(*eidx) * slab; dst = V1b; n = slab; }
  else                      { src = x;                          dst = Xb;  n = (long)T_DIM * D_DIM; }
  long stride = (long)gridDim.x * blockDim.x;
  for (long i = (long)blockIdx.x * blockDim.x + tid; i * 8 < n; i += stride) {
    long e = i * 8;
    const float4* p = (const float4*)(src + e);
    float4 f0 = p[0], f1 = p[1];
    u16x8 o;
    o[0] = f2bf(f0.x); o[1] = f2bf(f0.y); o[2] = f2bf(f0.z); o[3] = f2bf(f0.w);
    o[4] = f2bf(f1.x); o[5] = f2bf(f1.y); o[6] = f2bf(f1.z); o[7] = f2bf(f1.w);
    *(u16x8*)(dst + e) = o;
  }
}

// Counted vmcnt waits with memory clobber (stage issues pinned to their side
// of the wait so the outstanding-count arithmetic stays exact — r8/r9 lesson).
#define VMCNT8 asm volatile("s_waitcnt vmcnt(8)" ::: "memory")
#define VMCNT5 asm volatile("s_waitcnt vmcnt(5)" ::: "memory")
#define VMCNT0 asm volatile("s_waitcnt vmcnt(0)" ::: "memory")
// Barrier = lgkmcnt(0) drain + s_barrier (opaque). Invariant: a ds_read and a
// later global_load_lds stage overwriting the same LDS rows must be separated
// by one of these (r7-r10 lesson). vmcnt NOT drained here.
#define BAR asm volatile("s_waitcnt lgkmcnt(0)\n\ts_barrier" ::: "memory")
#define PRIO1 __builtin_amdgcn_s_setprio(1)
#define PRIO0 __builtin_amdgcn_s_setprio(0)

// ---------- GEMM1 fused, read-ahead pipelined 4-phase (r15-proven, FROZEN) ----------
// tile 256m x 128n(dual), BK=64, 8 waves 2Mx4N, wave 128x32 per GEMM.
// Frag reads >=1 phase ahead of MFMA use: aA(t)@p3(t-1), b1(t)@p4(t-1),
// aB(t)@p1(t), b2(t)@p2(t).
// Stages for t+2 (8 rounds): B1x2@p1, Ax3@p2, Ax1+B2x2@p3.
// One vmcnt(5)@p2 drains exactly tile t+1 (peak 13 outstanding -> 5).
// Prologue pre-reads followed by BAR (race fix: sampled before first stage).
__global__ __launch_bounds__(512, 1) void gemm1_silu(
    const unsigned short* __restrict__ Xb,    // (4096,2048)
    const unsigned short* __restrict__ W1b,   // (8192,2048)
    const unsigned short* __restrict__ V1b,   // (8192,2048)
    unsigned short* __restrict__ Hb) {        // (4096,8192)
  __shared__ __align__(16) unsigned short sA[2 * 16384];   // 256x64 per buf
  __shared__ __align__(16) unsigned short sB1[2 * 8192];   // 128x64
  __shared__ __align__(16) unsigned short sB2[2 * 8192];

  const int tid = threadIdx.x;
  const int wv = tid >> 6, l = tid & 63;
  const int wm = wv >> 2, wn = wv & 3;        // 2M x 4N
  const int kq = l >> 4, lr = l & 15;
  const int bsw = (blockIdx.x & 7) * 128 + (blockIdx.x >> 3);
  const int m0 = (bsw >> 6) << 8;             // 16 m-blocks
  const int n0 = (bsw & 63) << 7;             // 64 n-blocks

  const int rsub = tid >> 3;
  const int sslot8 = ((tid & 7) ^ ((tid >> 3) & 7)) << 3;
  const unsigned short* gA  = Xb  + (long)(m0 + rsub) * D_DIM + sslot8;
  const unsigned short* gB1 = W1b + (long)(n0 + rsub) * D_DIM + sslot8;
  const unsigned short* gB2 = V1b + (long)(n0 + rsub) * D_DIM + sslot8;

#define STG1(gbase, r_, tc_, lbase) \
  gload16((gbase) + (long)((r_) * 64) * D_DIM + (tc_), (lbase) + (r_) * 4096 + wv * 512)

  int aoffA[4], aoffB[4], boff[2];
#pragma unroll
  for (int j = 0; j < 4; ++j) {
    int rowA = wm * 64 + j * 16 + lr;          // A0 half: rows 0-127
    aoffA[j] = rowA * 64 + ((kq ^ (rowA & 7)) << 3);
    int rowB = 128 + wm * 64 + j * 16 + lr;    // A1 half: rows 128-255
    aoffB[j] = rowB * 64 + ((kq ^ (rowB & 7)) << 3);
  }
#pragma unroll
  for (int g = 0; g < 2; ++g) {
    int row = wn * 32 + g * 16 + lr;
    boff[g] = row * 64 + ((kq ^ (row & 7)) << 3);
  }

  f32x4 acc1[8][2], acc2[8][2];
  f32x4 z = {0.f, 0.f, 0.f, 0.f};
#pragma unroll
  for (int f = 0; f < 8; ++f)
#pragma unroll
    for (int g = 0; g < 2; ++g) { acc1[f][g] = z; acc2[f][g] = z; }

  bf16x8 aA[4][2], aB[4][2], b1[2][2], b2[2][2];

  // prologue: stage t0 (8 rounds) + t1 (8); drain t0; pre-read aA(0), b1(0);
  // then BAR so the pre-reads are sampled before P1(0)'s stage can overwrite.
  STG1(gB1, 0, 0, sB1); STG1(gB1, 1, 0, sB1);
  STG1(gA, 0, 0, sA); STG1(gA, 1, 0, sA); STG1(gA, 2, 0, sA); STG1(gA, 3, 0, sA);
  STG1(gB2, 0, 0, sB2); STG1(gB2, 1, 0, sB2);
  STG1(gB1, 0, 64, sB1 + 8192); STG1(gB1, 1, 64, sB1 + 8192);
  STG1(gA, 0, 64, sA + 16384); STG1(gA, 1, 64, sA + 16384);
  STG1(gA, 2, 64, sA + 16384); STG1(gA, 3, 64, sA + 16384);
  STG1(gB2, 0, 64, sB2 + 8192); STG1(gB2, 1, 64, sB2 + 8192);
  VMCNT8;
  BAR;
#pragma unroll
  for (int j = 0; j < 4; ++j) {
    aA[j][0] = *(const bf16x8*)(sA + aoffA[j]);
    aA[j][1] = *(const bf16x8*)(sA + (aoffA[j] ^ 32));
  }
#pragma unroll
  for (int g = 0; g < 2; ++g) {
    b1[g][0] = *(const bf16x8*)(sB1 + boff[g]);
    b1[g][1] = *(const bf16x8*)(sB1 + (boff[g] ^ 32));
  }
  BAR;   // pre-reads sampled before first loop stage (r11 race fix)

  const int NT = D_DIM / 64;  // 32
  for (int t = 0; t < NT; ++t) {
    const int db = t & 1, nx = db ^ 1;
    const unsigned short* Acur  = sA  + db * 16384;
    const unsigned short* Anxt  = sA  + nx * 16384;
    const unsigned short* B1nxt = sB1 + nx * 8192;
    const unsigned short* B2cur = sB2 + db * 8192;
    unsigned short* AcurW  = (unsigned short*)sA  + db * 16384;
    unsigned short* B1curW = (unsigned short*)sB1 + db * 8192;
    unsigned short* B2curW = (unsigned short*)sB2 + db * 8192;
    const int p1ok = (t + 1 < NT), p2ok = (t + 2 < NT);
    const int tc2 = (t + 2) << 6;

    // ---- P1: read aB(t); stage B1(t+2); MFMA acc1 A0xB1 ----
#pragma unroll
    for (int j = 0; j < 4; ++j) {
      aB[j][0] = *(const bf16x8*)(Acur + aoffB[j]);
      aB[j][1] = *(const bf16x8*)(Acur + (aoffB[j] ^ 32));
    }
    if (p2ok) { STG1(gB1, 0, tc2, B1curW); STG1(gB1, 1, tc2, B1curW); }
    PRIO1;
#pragma unroll
    for (int j = 0; j < 4; ++j)
#pragma unroll
      for (int g = 0; g < 2; ++g) {
        acc1[j][g] = __builtin_amdgcn_mfma_f32_16x16x32_bf16(aA[j][0], b1[g][0], acc1[j][g], 0, 0, 0);
        acc1[j][g] = __builtin_amdgcn_mfma_f32_16x16x32_bf16(aA[j][1], b1[g][1], acc1[j][g], 0, 0, 0);
      }
    PRIO0;
    BAR;

    // ---- P2: read b2(t); stage A(t+2) r0-2; MFMA acc1 A1xB1; vmcnt ----
#pragma unroll
    for (int g = 0; g < 2; ++g) {
      b2[g][0] = *(const bf16x8*)(B2cur + boff[g]);
      b2[g][1] = *(const bf16x8*)(B2cur + (boff[g] ^ 32));
    }
    if (p2ok) { STG1(gA, 0, tc2, AcurW); STG1(gA, 1, tc2, AcurW); STG1(gA, 2, tc2, AcurW); }
    PRIO1;
#pragma unroll
    for (int j = 0; j < 4; ++j)
#pragma unroll
      for (int g = 0; g < 2; ++g) {
        acc1[4 + j][g] = __builtin_amdgcn_mfma_f32_16x16x32_bf16(aB[j][0], b1[g][0], acc1[4 + j][g], 0, 0, 0);
        acc1[4 + j][g] = __builtin_amdgcn_mfma_f32_16x16x32_bf16(aB[j][1], b1[g][1], acc1[4 + j][g], 0, 0, 0);
      }
    PRIO0;
    if (p2ok) { VMCNT5; } else if (p1ok) { VMCNT0; }   // tile t+1 fully landed
    BAR;

    // ---- P3: stage A(t+2) r3 + B2(t+2); MFMA acc2 A0xB2; read aA(t+1) ----
    if (p2ok) { STG1(gA, 3, tc2, AcurW); STG1(gB2, 0, tc2, B2curW); STG1(gB2, 1, tc2, B2curW); }
    PRIO1;
#pragma unroll
    for (int j = 0; j < 4; ++j)
#pragma unroll
      for (int g = 0; g < 2; ++g) {
        acc2[j][g] = __builtin_amdgcn_mfma_f32_16x16x32_bf16(aA[j][0], b2[g][0], acc2[j][g], 0, 0, 0);
        acc2[j][g] = __builtin_amdgcn_mfma_f32_16x16x32_bf16(aA[j][1], b2[g][1], acc2[j][g], 0, 0, 0);
      }
    PRIO0;
    if (p1ok) {
#pragma unroll
      for (int j = 0; j < 4; ++j) {
        aA[j][0] = *(const bf16x8*)(Anxt + aoffA[j]);
        aA[j][1] = *(const bf16x8*)(Anxt + (aoffA[j] ^ 32));
      }
    }
    BAR;

    // ---- P4: MFMA acc2 A1xB2; read b1(t+1) ----
    PRIO1;
#pragma unroll
    for (int j = 0; j < 4; ++j)
#pragma unroll
      for (int g = 0; g < 2; ++g) {
        acc2[4 + j][g] = __builtin_amdgcn_mfma_f32_16x16x32_bf16(aB[j][0], b2[g][0], acc2[4 + j][g], 0, 0, 0);
        acc2[4 + j][g] = __builtin_amdgcn_mfma_f32_16x16x32_bf16(aB[j][1], b2[g][1], acc2[4 + j][g], 0, 0, 0);
      }
    PRIO0;
    if (p1ok) {
#pragma unroll
      for (int g = 0; g < 2; ++g) {
        b1[g][0] = *(const bf16x8*)(B1nxt + boff[g]);
        b1[g][1] = *(const bf16x8*)(B1nxt + (boff[g] ^ 32));
      }
    }
    BAR;
  }

  // epilogue: h = silu(x1)*x2, bf16
#pragma unroll
  for (int f = 0; f < 8; ++f)
#pragma unroll
    for (int g = 0; g < 2; ++g)
#pragma unroll
      for (int r = 0; r < 4; ++r) {
        int row = m0 + (f >> 2) * 128 + wm * 64 + (f & 3) * 16 + kq * 4 + r;
        int col = n0 + wn * 32 + g * 16 + lr;
        float x1 = acc1[f][g][r], x2 = acc2[f][g][r];
        float hv = x1 / (1.f + __expf(-x1)) * x2;
        Hb[(long)row * FFN_DIM + col] = f2bf(hv);
      }
#undef STG1
}

// ---------- GEMM2 (r18-proven, FROZEN): 128x128, BK=64, 4 waves, 2 blocks/CU ----
__global__ __launch_bounds__(256, 2) void gemm2(
    const unsigned short* __restrict__ Hb,    // (4096,8192)
    const unsigned short* __restrict__ W2T,   // (2048,8192)
    float* __restrict__ out) {                // (4096,2048)
  __shared__ __align__(16) unsigned short sA[2 * 8192];   // [buf][128x64]
  __shared__ __align__(16) unsigned short sB[2 * 8192];

  const int tid = threadIdx.x;
  const int wv = tid >> 6, l = tid & 63;
  const int wm = wv >> 1, wn = wv & 1;        // 2M x 2N, wave 64x64
  const int kq = l >> 4, lr = l & 15;
  const int bsw = (blockIdx.x & 7) * 64 + (blockIdx.x >> 3);   // 512 = 8*64
  const int m0 = (bsw >> 4) << 7;             // 32 m-tiles
  const int n0 = (bsw & 15) << 7;             // 16 n-tiles

  const int rsub = tid >> 3;                  // 0..31
  const int sslot8 = ((tid & 7) ^ (rsub & 7)) << 3;
  const unsigned short* gA = Hb  + (long)(m0 + rsub) * FFN_DIM + sslot8;
  const unsigned short* gB = W2T + (long)(n0 + rsub) * FFN_DIM + sslot8;

#define STG2(gbase, r_, tc_, lbase) \
  gload16((gbase) + (long)((r_) * 32) * FFN_DIM + (tc_), (lbase) + (r_) * 2048 + wv * 512)

  int aoff[4], boff[4];
#pragma unroll
  for (int f = 0; f < 4; ++f) {
    int row = wm * 64 + f * 16 + lr;
    aoff[f] = row * 64 + ((kq ^ (row & 7)) << 3);
  }
#pragma unroll
  for (int g = 0; g < 4; ++g) {
    int row = wn * 64 + g * 16 + lr;
    boff[g] = row * 64 + ((kq ^ (row & 7)) << 3);
  }

  f32x4 acc[4][4];
  f32x4 z = {0.f, 0.f, 0.f, 0.f};
#pragma unroll
  for (int f = 0; f < 4; ++f)
#pragma unroll
    for (int g = 0; g < 4; ++g) acc[f][g] = z;

  STG2(gA, 0, 0, sA); STG2(gA, 1, 0, sA); STG2(gA, 2, 0, sA); STG2(gA, 3, 0, sA);
  STG2(gB, 0, 0, sB); STG2(gB, 1, 0, sB); STG2(gB, 2, 0, sB); STG2(gB, 3, 0, sB);
  STG2(gA, 0, 64, sA + 8192); STG2(gA, 1, 64, sA + 8192);
  STG2(gA, 2, 64, sA + 8192); STG2(gA, 3, 64, sA + 8192);
  STG2(gB, 0, 64, sB + 8192); STG2(gB, 1, 64, sB + 8192);
  STG2(gB, 2, 64, sB + 8192); STG2(gB, 3, 64, sB + 8192);
  VMCNT8;
  BAR;

  const int NT = FFN_DIM / 64;  // 128
  for (int t = 0; t < NT; ++t) {
    const int cur = t & 1;
    const unsigned short* Ac = sA + cur * 8192;
    const unsigned short* Bc = sB + cur * 8192;
    unsigned short* AcW = (unsigned short*)sA + cur * 8192;
    unsigned short* BcW = (unsigned short*)sB + cur * 8192;
    bf16x8 af[4][2], bf_[4][2];

#pragma unroll
    for (int f = 0; f < 4; ++f) {
      af[f][0] = *(const bf16x8*)(Ac + aoff[f]);
      af[f][1] = *(const bf16x8*)(Ac + (aoff[f] ^ 32));
    }
#pragma unroll
    for (int g = 0; g < 4; ++g) {
      bf_[g][0] = *(const bf16x8*)(Bc + boff[g]);
      bf_[g][1] = *(const bf16x8*)(Bc + (boff[g] ^ 32));
    }
    PRIO1;
#pragma unroll
    for (int f = 0; f < 4; ++f)
#pragma unroll
      for (int g = 0; g < 4; ++g) {
        acc[f][g] = __builtin_amdgcn_mfma_f32_16x16x32_bf16(af[f][0], bf_[g][0], acc[f][g], 0, 0, 0);
        acc[f][g] = __builtin_amdgcn_mfma_f32_16x16x32_bf16(af[f][1], bf_[g][1], acc[f][g], 0, 0, 0);
      }
    PRIO0;
    BAR;

    if (t + 2 < NT) {
      const int tc2 = (t + 2) << 6;
      STG2(gA, 0, tc2, AcW); STG2(gA, 1, tc2, AcW);
      STG2(gA, 2, tc2, AcW); STG2(gA, 3, tc2, AcW);
      STG2(gB, 0, tc2, BcW); STG2(gB, 1, tc2, BcW);
      STG2(gB, 2, tc2, BcW); STG2(gB, 3, tc2, BcW);
      VMCNT8;
    } else if (t + 1 < NT) {
      VMCNT0;
    }
    BAR;
  }

#pragma unroll
  for (int f = 0; f < 4; ++f)
#pragma unroll
    for (int g = 0; g < 4; ++g)
#pragma unroll
      for (int r = 0; r < 4; ++r) {
        int row = m0 + wm * 64 + f * 16 + kq * 4 + r;
        int col = n0 + wn * 64 + g * 16 + lr;
        out[(long)row * D_DIM + col] = acc[f][g][r];
      }
#undef STG2
}

extern "C" void kernel_launch(void* const* d_in, const int* in_sizes, int n_in,
                              void* d_out, int out_size, void* d_ws, size_t ws_size,
                              hipStream_t stream) {
  const float* x  = (const float*)d_in[0];
  const float* w1 = (const float*)d_in[1];
  const float* v1 = (const float*)d_in[2];
  const float* w2 = (const float*)d_in[3];
  const int* eidx = (const int*)d_in[4];

  char* ws = (char*)d_ws;
  unsigned short* Xb  = (unsigned short*)(ws);                  // 16 MiB
  unsigned short* W1b = (unsigned short*)(ws + (16l << 20));    // 32 MiB
  unsigned short* V1b = (unsigned short*)(ws + (48l << 20));    // 32 MiB
  unsigned short* W2T = (unsigned short*)(ws + (80l << 20));    // 32 MiB
  unsigned short* Hb  = (unsigned short*)(ws + (112l << 20));   // 64 MiB
  float* out = (float*)d_out;

  prep4_kernel<<<dim3(4096, 4), 512, 0, stream>>>(x, w1, v1, w2, eidx, Xb, W1b, V1b, W2T);
  gemm1_silu<<<1024, 512, 0, stream>>>(Xb, W1b, V1b, Hb);
  gemm2<<<512, 256, 0, stream>>>(Hb, W2T, out);
}